// Round 5
// baseline (498.635 us; speedup 1.0000x reference)
//
#include <hip/hip_runtime.h>
#include <cstdint>
#include <cstddef>

// MultiHeadSelfAttention: B=4 H=16 S=2048 D=1024 d=64
// d_out = [output fp32 (4,2048,1024)] ++ [attn_weights fp32 (4,16,2048,2048)]
//
// R5: (a) attn pass A: 4-buffer K rotation, depth-3 prefetch, counted
//         s_waitcnt vmcnt(2) + raw s_barrier (T4) -- no full drains;
//     (b) XCD-aware bijective block swizzle on attn + GEMMs (T1);
//     (c) QKV fused into one N=3072 GEMM (concatenated bf16 weights).

#define D_MODEL 1024
#define NHEADS  16
#define HDIM    64
#define BATCH   4
#define SEQ     2048
#define NTOK    (BATCH*SEQ)   // 8192

typedef __bf16 bf16x8 __attribute__((ext_vector_type(8)));
typedef float  f32x4  __attribute__((ext_vector_type(4)));
typedef unsigned short u16x8 __attribute__((ext_vector_type(8)));

__device__ __forceinline__ uint16_t f2bf(float f) {
  union { float f; uint32_t u; } v; v.f = f;
  return (uint16_t)((v.u + 0x7FFFu + ((v.u >> 16) & 1u)) >> 16);
}
__device__ __forceinline__ float bf2f(uint16_t u) {
  union { uint32_t u; float f; } v; v.u = (uint32_t)u << 16; return v.f;
}
__device__ __forceinline__ bf16x8 ldbf8(const uint16_t* p) {
  return __builtin_bit_cast(bf16x8, *(const u16x8*)p);
}
#define MFMA16(a, b, c) __builtin_amdgcn_mfma_f32_16x16x32_bf16((a), (b), (c), 0, 0, 0)

// async global->LDS, 16B/lane; LDS dest = wave-uniform base + lane*16.
__device__ __forceinline__ void gl_lds16(const uint16_t* g, uint16_t* l) {
  __builtin_amdgcn_global_load_lds(
      (const __attribute__((address_space(1))) uint32_t*)g,
      (__attribute__((address_space(3))) uint32_t*)l, 16, 0, 0);
}

// ---------------- fp32 -> bf16 convert ----------------
__global__ __launch_bounds__(256) void cvt_kernel(const float* __restrict__ src,
                                                  uint16_t* __restrict__ dst, int n4) {
  int i = blockIdx.x * blockDim.x + threadIdx.x;
  if (i < n4) {
    float4 f = ((const float4*)src)[i];
    ushort4 o;
    o.x = f2bf(f.x); o.y = f2bf(f.y); o.z = f2bf(f.z); o.w = f2bf(f.w);
    ((ushort4*)dst)[i] = o;
  }
}

// ---------------- fused QKV GEMM ----------------
// A[8192,1024] bf16; Wqkv[3072,1024] bf16 (rows: wq | wk | wv).
// out[m,n] = A[m,:] . Wqkv[n,:] + bias_seg[n%1024]
// seg 0 -> Qb bf16 [tok,1024]; seg 1 -> Kc bf16 [tok,1024];
// seg 2 -> Vt bf16 per head [(b,h,d),s].
// 128x128 tile, BK=64, gload_lds w16, 1D grid 1536 with XCD swizzle.
__global__ __launch_bounds__(256)
void gemm_qkv(const uint16_t* __restrict__ A, const uint16_t* __restrict__ Wqkv,
              const float* __restrict__ bq, const float* __restrict__ bk,
              const float* __restrict__ bv,
              uint16_t* __restrict__ Qb, uint16_t* __restrict__ Kc,
              uint16_t* __restrict__ Vt) {
  __shared__ uint16_t As[128 * 64];
  __shared__ uint16_t Bs[128 * 64];
  const int flat = blockIdx.x;                 // 1536 blocks
  const int l = (flat & 7) * 192 + (flat >> 3);
  const int bx = l % 24, by = l / 24;
  const int tid  = threadIdx.x;
  const int lane = tid & 63;
  const int wave = tid >> 6;
  const int wr = wave >> 1, wc = wave & 1;
  const int m0 = by * 128, n0 = bx * 128;
  const int lrow = lane & 15;
  const int grp  = lane >> 4;
  const int l8   = lane >> 3;
  const int c8   = lane & 7;

  f32x4 acc[4][4] = {};

  for (int k0 = 0; k0 < 1024; k0 += 64) {
#pragma unroll
    for (int it = 0; it < 4; ++it) {
      const int chunk = wave * 4 + it;
      const int row = chunk * 8 + l8;
      gl_lds16(&A   [(size_t)(m0 + row) * 1024 + k0 + c8 * 8], &As[chunk * 512]);
      gl_lds16(&Wqkv[(size_t)(n0 + row) * 1024 + k0 + c8 * 8], &Bs[chunk * 512]);
    }
    __syncthreads();
#pragma unroll
    for (int ks = 0; ks < 2; ++ks) {
      bf16x8 af[4], bfr[4];
#pragma unroll
      for (int i = 0; i < 4; ++i) {
        af [i] = ldbf8(&As[(wr * 64 + i * 16 + lrow) * 64 + ks * 32 + grp * 8]);
        bfr[i] = ldbf8(&Bs[(wc * 64 + i * 16 + lrow) * 64 + ks * 32 + grp * 8]);
      }
#pragma unroll
      for (int i = 0; i < 4; ++i)
#pragma unroll
        for (int j = 0; j < 4; ++j)
          acc[i][j] = MFMA16(af[i], bfr[j], acc[i][j]);
    }
    __syncthreads();
  }

  const int seg = n0 >> 10;                    // uniform per block
  const float* bp = (seg == 0) ? bq : (seg == 1) ? bk : bv;
  uint16_t* dst01 = (seg == 0) ? Qb : Kc;
  const int r0 = grp * 4;
#pragma unroll
  for (int i = 0; i < 4; ++i) {
#pragma unroll
    for (int j = 0; j < 4; ++j) {
      int gmb = m0 + wr * 64 + i * 16 + r0;
      int gn  = n0 + wc * 64 + j * 16 + lrow;
      int nloc = gn & 1023;
      float bv_ = bp[nloc];
#pragma unroll
      for (int r = 0; r < 4; ++r) {
        float v = acc[i][j][r] + bv_;
        int gm = gmb + r;
        if (seg < 2) {
          dst01[(size_t)gm * 1024 + nloc] = f2bf(v);
        } else {
          int b = gm >> 11, s = gm & (SEQ - 1);
          int h = nloc >> 6, d = nloc & (HDIM - 1);
          Vt[(((size_t)(b * NHEADS + h) * HDIM + d) << 11) + s] = f2bf(v);
        }
      }
    }
  }
}

// ---------------- out-proj GEMM (fp32 out) ----------------
__global__ __launch_bounds__(256)
void gemm_out(const uint16_t* __restrict__ A, const uint16_t* __restrict__ Bt,
              const float* __restrict__ bias, float* __restrict__ out) {
  __shared__ uint16_t As[128 * 64];
  __shared__ uint16_t Bs[128 * 64];
  const int flat = blockIdx.x;                 // 512 blocks
  const int l = (flat & 7) * 64 + (flat >> 3);
  const int bx = l & 7, by = l >> 3;
  const int tid  = threadIdx.x;
  const int lane = tid & 63;
  const int wave = tid >> 6;
  const int wr = wave >> 1, wc = wave & 1;
  const int m0 = by * 128, n0 = bx * 128;
  const int lrow = lane & 15;
  const int grp  = lane >> 4;
  const int l8   = lane >> 3;
  const int c8   = lane & 7;

  f32x4 acc[4][4] = {};

  for (int k0 = 0; k0 < 1024; k0 += 64) {
#pragma unroll
    for (int it = 0; it < 4; ++it) {
      const int chunk = wave * 4 + it;
      const int row = chunk * 8 + l8;
      gl_lds16(&A [(size_t)(m0 + row) * 1024 + k0 + c8 * 8], &As[chunk * 512]);
      gl_lds16(&Bt[(size_t)(n0 + row) * 1024 + k0 + c8 * 8], &Bs[chunk * 512]);
    }
    __syncthreads();
#pragma unroll
    for (int ks = 0; ks < 2; ++ks) {
      bf16x8 af[4], bfr[4];
#pragma unroll
      for (int i = 0; i < 4; ++i) {
        af [i] = ldbf8(&As[(wr * 64 + i * 16 + lrow) * 64 + ks * 32 + grp * 8]);
        bfr[i] = ldbf8(&Bs[(wc * 64 + i * 16 + lrow) * 64 + ks * 32 + grp * 8]);
      }
#pragma unroll
      for (int i = 0; i < 4; ++i)
#pragma unroll
        for (int j = 0; j < 4; ++j)
          acc[i][j] = MFMA16(af[i], bfr[j], acc[i][j]);
    }
    __syncthreads();
  }

  const int r0 = grp * 4;
#pragma unroll
  for (int i = 0; i < 4; ++i) {
#pragma unroll
    for (int j = 0; j < 4; ++j) {
      int gmb = m0 + wr * 64 + i * 16 + r0;
      int gn  = n0 + wc * 64 + j * 16 + lrow;
      float bv = bias[gn];
#pragma unroll
      for (int r = 0; r < 4; ++r)
        out[(size_t)(gmb + r) * 1024 + gn] = acc[i][j][r] + bv;
    }
  }
}

// ---------------- Attention ----------------
// LDS tile: element (row, colblk c) at lds[row*64 + (c ^ (row&7))*8]
// (linear gload_lds writes; XOR applied on pre-swizzled source + read side)
__device__ __forceinline__ bf16x8 rd_tile(const uint16_t* t, int r, int s) {
  return ldbf8(&t[r * 64 + ((s ^ (r & 7)) * 8)]);
}

#define QBLK 128
// 1D grid 1024 (XCD-swizzled), 512 thr = 8 waves; wave owns 16 q rows.
// mfma(K,Q): lane holds scores for q=lane&15, k_loc=(lane>>4)*4+r.
__global__ __launch_bounds__(512)
void attn_kernel(const uint16_t* __restrict__ Q, const uint16_t* __restrict__ Kb,
                 const uint16_t* __restrict__ Vt, float* __restrict__ attnw,
                 uint16_t* __restrict__ ctx) {
  __shared__ uint16_t Ks[2][64 * 64];
  __shared__ uint16_t Vs[2][64 * 64];
  __shared__ uint16_t Pl[8][16 * 72];
  const int tid  = threadIdx.x;
  const int lane = tid & 63;
  const int wave = tid >> 6;          // 0..7
  const int flat = blockIdx.x;        // 1024 blocks
  const int lb = (flat & 7) * 128 + (flat >> 3);   // 128 consecutive per XCD
  const int qt = lb & 15, h = (lb >> 4) & 15, b = lb >> 8;
  const int q0 = qt * QBLK + wave * 16;
  const int lrow = lane & 15;
  const int grp  = lane >> 4;
  const float c = 0.125f * 1.44269504088896f;  // (1/sqrt(64)) * log2(e)

  const uint16_t* Kh = Kb + (size_t)(b * SEQ) * D_MODEL + h * HDIM;   // [s][d] str 1024
  const uint16_t* Vh = Vt + ((size_t)(b * NHEADS + h) * HDIM) * SEQ;  // [d][s] str 2048

  const size_t qbase = ((size_t)(b * SEQ) + q0 + lrow) * D_MODEL + h * HDIM;
  const bf16x8 qf0 = ldbf8(&Q[qbase + grp * 8]);
  const bf16x8 qf1 = ldbf8(&Q[qbase + 32 + grp * 8]);

  // staging coords: wave stages rows [wave*8, wave*8+8) of each 64x64 tile
  const int srow = wave * 8 + (lane >> 3);
  const int scb  = (lane & 7) ^ (srow & 7);        // pre-swizzled source col-blk

  uint16_t* const B0 = Ks[0];
  uint16_t* const B1 = Ks[1];
  uint16_t* const B2 = Vs[0];
  uint16_t* const B3 = Vs[1];

  // ---- pass A: online max+sum; 4-buffer rotation, depth-3 prefetch ----
  float m = -INFINITY, l = 0.f;
  auto issueK = [&](int j, uint16_t* buf) {
    gl_lds16(&Kh[(size_t)(j * 64 + srow) * D_MODEL + scb * 8], &buf[wave * 512]);
  };
  auto stepA = [&](const uint16_t* tile) {
    f32x4 s[4];
#pragma unroll
    for (int kt = 0; kt < 4; ++kt) {
      f32x4 a = {};
      a = MFMA16(rd_tile(tile, kt * 16 + lrow, grp),     qf0, a);
      a = MFMA16(rd_tile(tile, kt * 16 + lrow, 4 + grp), qf1, a);
      s[kt] = a;
    }
    float v[16];
#pragma unroll
    for (int kt = 0; kt < 4; ++kt)
#pragma unroll
      for (int r = 0; r < 4; ++r) v[kt * 4 + r] = s[kt][r] * c;
    float mx = v[0];
#pragma unroll
    for (int i = 1; i < 16; ++i) mx = fmaxf(mx, v[i]);
    float mn = fmaxf(m, mx);
    float sum = 0.f;
#pragma unroll
    for (int i = 0; i < 16; ++i) sum += __builtin_amdgcn_exp2f(v[i] - mn);
    l = l * __builtin_amdgcn_exp2f(m - mn) + sum;
    m = mn;
  };
#define VWB(N) do { asm volatile("s_waitcnt vmcnt(" #N ")" ::: "memory"); \
    __builtin_amdgcn_s_barrier(); __builtin_amdgcn_sched_barrier(0); } while (0)

  issueK(0, B0); issueK(1, B1); issueK(2, B2);
#pragma unroll 1
  for (int kc = 0; kc < 28; kc += 4) {
    VWB(2); issueK(kc + 3, B3); stepA(B0);
    VWB(2); issueK(kc + 4, B0); stepA(B1);
    VWB(2); issueK(kc + 5, B1); stepA(B2);
    VWB(2); issueK(kc + 6, B2); stepA(B3);
  }
  VWB(2); issueK(31, B3); stepA(B0);   // chunk 28
  VWB(2); stepA(B1);                   // chunk 29
  VWB(1); stepA(B2);                   // chunk 30
  VWB(0); stepA(B3);                   // chunk 31

#pragma unroll
  for (int d = 16; d <= 32; d <<= 1) {
    float mp = __shfl_xor(m, d), lp = __shfl_xor(l, d);
    float mn = fmaxf(m, mp);
    l = l * __builtin_amdgcn_exp2f(m - mn) + lp * __builtin_amdgcn_exp2f(mp - mn);
    m = mn;
  }
  const float rinv = 1.0f / l;

  // ---- pass B: recompute scores, weights + PV; K+V double-buffered ----
  f32x4 cacc[4] = {};
  uint16_t* pw = &Pl[wave][0];
  float* awc = attnw + (((size_t)(b * NHEADS + h)) * SEQ + q0) * SEQ;
  gl_lds16(&Kh[(size_t)srow * D_MODEL + scb * 8], &Ks[0][wave * 512]);
  gl_lds16(&Vh[(size_t)srow * SEQ + scb * 8],     &Vs[0][wave * 512]);
#pragma unroll 1
  for (int kc = 0; kc < SEQ / 64; ++kc) {
    const int cur = kc & 1;
    __syncthreads();
    if (kc + 1 < SEQ / 64) {
      gl_lds16(&Kh[(size_t)((kc + 1) * 64 + srow) * D_MODEL + scb * 8],
               &Ks[cur ^ 1][wave * 512]);
      gl_lds16(&Vh[(size_t)srow * SEQ + (kc + 1) * 64 + scb * 8],
               &Vs[cur ^ 1][wave * 512]);
    }
    const uint16_t* kt_ = Ks[cur];
    f32x4 s[4];
#pragma unroll
    for (int kt = 0; kt < 4; ++kt) {
      f32x4 a = {};
      a = MFMA16(rd_tile(kt_, kt * 16 + lrow, grp),     qf0, a);
      a = MFMA16(rd_tile(kt_, kt * 16 + lrow, 4 + grp), qf1, a);
      s[kt] = a;
    }
#pragma unroll
    for (int kt = 0; kt < 4; ++kt) {
      ushort4 w;
      w.x = f2bf(__builtin_amdgcn_exp2f(s[kt][0] * c - m) * rinv);
      w.y = f2bf(__builtin_amdgcn_exp2f(s[kt][1] * c - m) * rinv);
      w.z = f2bf(__builtin_amdgcn_exp2f(s[kt][2] * c - m) * rinv);
      w.w = f2bf(__builtin_amdgcn_exp2f(s[kt][3] * c - m) * rinv);
      *(ushort4*)&pw[lrow * 72 + kt * 16 + grp * 4] = w;
    }
    asm volatile("s_waitcnt lgkmcnt(0)" ::: "memory");
    // coalesced fp32 weight stores: 4 instrs x (4 q-rows x 256B)
#pragma unroll
    for (int ii = 0; ii < 4; ++ii) {
      int q = ii * 4 + grp;
      ushort4 t4 = *(const ushort4*)&pw[q * 72 + lrow * 4];
      float4 o = make_float4(bf2f(t4.x), bf2f(t4.y), bf2f(t4.z), bf2f(t4.w));
      *(float4*)&awc[(size_t)q * SEQ + kc * 64 + lrow * 4] = o;
    }
    // PV over this 64-key chunk
    const uint16_t* vt_ = Vs[cur];
#pragma unroll
    for (int ks = 0; ks < 2; ++ks) {
      const bf16x8 pf = ldbf8(&pw[lrow * 72 + ks * 32 + grp * 8]);
#pragma unroll
      for (int n = 0; n < 4; ++n) {
        const bf16x8 vf = rd_tile(vt_, n * 16 + lrow, ks * 4 + grp);
        cacc[n] = MFMA16(pf, vf, cacc[n]);
      }
    }
  }
  // ctx: lane holds ctx[q = grp*4+r][d = n*16+lrow]
#pragma unroll
  for (int n = 0; n < 4; ++n)
#pragma unroll
    for (int r = 0; r < 4; ++r) {
      int gq = q0 + grp * 4 + r;
      ctx[((size_t)(b * SEQ) + gq) * D_MODEL + h * HDIM + n * 16 + lrow] = f2bf(cacc[n][r]);
    }
}

// ---------------- launch ----------------
extern "C" void kernel_launch(void* const* d_in, const int* in_sizes, int n_in,
                              void* d_out, int out_size, void* d_ws, size_t ws_size,
                              hipStream_t stream) {
  const float* x  = (const float*)d_in[0];
  const float* wq = (const float*)d_in[1];
  const float* bq = (const float*)d_in[2];
  const float* wk = (const float*)d_in[3];
  const float* bk = (const float*)d_in[4];
  const float* wv = (const float*)d_in[5];
  const float* bv = (const float*)d_in[6];
  const float* wo = (const float*)d_in[7];
  const float* bo = (const float*)d_in[8];

  char* ws = (char*)d_ws;
  uint16_t* xb   = (uint16_t*)ws;                   // 16 MB (reused as ctx)
  uint16_t* wqkv = (uint16_t*)(ws + (16u << 20));   // 6 MB: wq|wk|wv rows
  uint16_t* wob  = (uint16_t*)(ws + (22u << 20));   // 2 MB
  uint16_t* Qb   = (uint16_t*)(ws + (24u << 20));
  uint16_t* Kc   = (uint16_t*)(ws + (40u << 20));
  uint16_t* Vtb  = (uint16_t*)(ws + (56u << 20));
  uint16_t* ctx  = xb;

  float* outp  = (float*)d_out;
  float* attnw = outp + (size_t)NTOK * D_MODEL;

  {
    int n4 = (NTOK * D_MODEL) / 4;
    cvt_kernel<<<(n4 + 255) / 256, 256, 0, stream>>>(x, xb, n4);
    int w4 = (D_MODEL * D_MODEL) / 4;
    cvt_kernel<<<(w4 + 255) / 256, 256, 0, stream>>>(wq, wqkv, w4);
    cvt_kernel<<<(w4 + 255) / 256, 256, 0, stream>>>(wk, wqkv + (size_t)D_MODEL * D_MODEL, w4);
    cvt_kernel<<<(w4 + 255) / 256, 256, 0, stream>>>(wv, wqkv + 2 * (size_t)D_MODEL * D_MODEL, w4);
    cvt_kernel<<<(w4 + 255) / 256, 256, 0, stream>>>(wo, wob, w4);
  }

  gemm_qkv<<<1536, 256, 0, stream>>>(xb, wqkv, bq, bk, bv, Qb, Kc, Vtb);

  attn_kernel<<<1024, 512, 0, stream>>>(Qb, Kc, Vtb, attnw, ctx);

  gemm_out<<<512, 256, 0, stream>>>(ctx, wob, bo, outp);
}

// Round 6
// 468.064 us; speedup vs baseline: 1.0653x; 1.0653x over previous
//
#include <hip/hip_runtime.h>
#include <cstdint>
#include <cstddef>

// MultiHeadSelfAttention: B=4 H=16 S=2048 D=1024 d=64
// d_out = [output fp32 (4,2048,1024)] ++ [attn_weights fp32 (4,16,2048,2048)]
//
// R6: revert attn pass-A to R4's proven depth-1 __syncthreads double-buffer
//     (R5's counted-vmcnt rotation + sched_barrier pinning = prime regression
//     suspect, m141 mechanism). Keep R5's fused QKV GEMM, gemm_out, XCD
//     swizzles. Fuse the 4 weight converts into one launch.

#define D_MODEL 1024
#define NHEADS  16
#define HDIM    64
#define BATCH   4
#define SEQ     2048
#define NTOK    (BATCH*SEQ)   // 8192

typedef __bf16 bf16x8 __attribute__((ext_vector_type(8)));
typedef float  f32x4  __attribute__((ext_vector_type(4)));
typedef unsigned short u16x8 __attribute__((ext_vector_type(8)));

__device__ __forceinline__ uint16_t f2bf(float f) {
  union { float f; uint32_t u; } v; v.f = f;
  return (uint16_t)((v.u + 0x7FFFu + ((v.u >> 16) & 1u)) >> 16);
}
__device__ __forceinline__ float bf2f(uint16_t u) {
  union { uint32_t u; float f; } v; v.u = (uint32_t)u << 16; return v.f;
}
__device__ __forceinline__ bf16x8 ldbf8(const uint16_t* p) {
  return __builtin_bit_cast(bf16x8, *(const u16x8*)p);
}
#define MFMA16(a, b, c) __builtin_amdgcn_mfma_f32_16x16x32_bf16((a), (b), (c), 0, 0, 0)

// async global->LDS, 16B/lane; LDS dest = wave-uniform base + lane*16.
__device__ __forceinline__ void gl_lds16(const uint16_t* g, uint16_t* l) {
  __builtin_amdgcn_global_load_lds(
      (const __attribute__((address_space(1))) uint32_t*)g,
      (__attribute__((address_space(3))) uint32_t*)l, 16, 0, 0);
}

// ---------------- fp32 -> bf16 converts ----------------
__global__ __launch_bounds__(256) void cvt_kernel(const float* __restrict__ src,
                                                  uint16_t* __restrict__ dst, int n4) {
  int i = blockIdx.x * blockDim.x + threadIdx.x;
  if (i < n4) {
    float4 f = ((const float4*)src)[i];
    ushort4 o;
    o.x = f2bf(f.x); o.y = f2bf(f.y); o.z = f2bf(f.z); o.w = f2bf(f.w);
    ((ushort4*)dst)[i] = o;
  }
}
// all 4 weight matrices -> contiguous bf16 dst (wq|wk|wv|wo), one launch
__global__ __launch_bounds__(256)
void cvt_w_kernel(const float* __restrict__ wq, const float* __restrict__ wk,
                  const float* __restrict__ wv, const float* __restrict__ wo,
                  uint16_t* __restrict__ dst) {
  int i = blockIdx.x * blockDim.x + threadIdx.x;   // [0, 4*262144)
  int sel = i >> 18, off = i & 262143;
  const float* src = (sel == 0) ? wq : (sel == 1) ? wk : (sel == 2) ? wv : wo;
  float4 f = ((const float4*)src)[off];
  ushort4 o;
  o.x = f2bf(f.x); o.y = f2bf(f.y); o.z = f2bf(f.z); o.w = f2bf(f.w);
  ((ushort4*)dst)[i] = o;
}

// ---------------- fused QKV GEMM ----------------
// A[8192,1024] bf16; Wqkv[3072,1024] bf16 (rows: wq | wk | wv).
// seg 0 -> Qb bf16 [tok,1024]; seg 1 -> Kc bf16; seg 2 -> Vt bf16 [(b,h,d),s].
__global__ __launch_bounds__(256)
void gemm_qkv(const uint16_t* __restrict__ A, const uint16_t* __restrict__ Wqkv,
              const float* __restrict__ bq, const float* __restrict__ bk,
              const float* __restrict__ bv,
              uint16_t* __restrict__ Qb, uint16_t* __restrict__ Kc,
              uint16_t* __restrict__ Vt) {
  __shared__ uint16_t As[128 * 64];
  __shared__ uint16_t Bs[128 * 64];
  const int flat = blockIdx.x;                 // 1536 blocks
  const int l = (flat & 7) * 192 + (flat >> 3);
  const int bx = l % 24, by = l / 24;
  const int tid  = threadIdx.x;
  const int lane = tid & 63;
  const int wave = tid >> 6;
  const int wr = wave >> 1, wc = wave & 1;
  const int m0 = by * 128, n0 = bx * 128;
  const int lrow = lane & 15;
  const int grp  = lane >> 4;
  const int l8   = lane >> 3;
  const int c8   = lane & 7;

  f32x4 acc[4][4] = {};

  for (int k0 = 0; k0 < 1024; k0 += 64) {
#pragma unroll
    for (int it = 0; it < 4; ++it) {
      const int chunk = wave * 4 + it;
      const int row = chunk * 8 + l8;
      gl_lds16(&A   [(size_t)(m0 + row) * 1024 + k0 + c8 * 8], &As[chunk * 512]);
      gl_lds16(&Wqkv[(size_t)(n0 + row) * 1024 + k0 + c8 * 8], &Bs[chunk * 512]);
    }
    __syncthreads();
#pragma unroll
    for (int ks = 0; ks < 2; ++ks) {
      bf16x8 af[4], bfr[4];
#pragma unroll
      for (int i = 0; i < 4; ++i) {
        af [i] = ldbf8(&As[(wr * 64 + i * 16 + lrow) * 64 + ks * 32 + grp * 8]);
        bfr[i] = ldbf8(&Bs[(wc * 64 + i * 16 + lrow) * 64 + ks * 32 + grp * 8]);
      }
#pragma unroll
      for (int i = 0; i < 4; ++i)
#pragma unroll
        for (int j = 0; j < 4; ++j)
          acc[i][j] = MFMA16(af[i], bfr[j], acc[i][j]);
    }
    __syncthreads();
  }

  const int seg = n0 >> 10;                    // uniform per block
  const float* bp = (seg == 0) ? bq : (seg == 1) ? bk : bv;
  uint16_t* dst01 = (seg == 0) ? Qb : Kc;
  const int r0 = grp * 4;
#pragma unroll
  for (int i = 0; i < 4; ++i) {
#pragma unroll
    for (int j = 0; j < 4; ++j) {
      int gmb = m0 + wr * 64 + i * 16 + r0;
      int gn  = n0 + wc * 64 + j * 16 + lrow;
      int nloc = gn & 1023;
      float bv_ = bp[nloc];
#pragma unroll
      for (int r = 0; r < 4; ++r) {
        float v = acc[i][j][r] + bv_;
        int gm = gmb + r;
        if (seg < 2) {
          dst01[(size_t)gm * 1024 + nloc] = f2bf(v);
        } else {
          int b = gm >> 11, s = gm & (SEQ - 1);
          int h = nloc >> 6, d = nloc & (HDIM - 1);
          Vt[(((size_t)(b * NHEADS + h) * HDIM + d) << 11) + s] = f2bf(v);
        }
      }
    }
  }
}

// ---------------- out-proj GEMM (fp32 out) ----------------
__global__ __launch_bounds__(256)
void gemm_out(const uint16_t* __restrict__ A, const uint16_t* __restrict__ Bt,
              const float* __restrict__ bias, float* __restrict__ out) {
  __shared__ uint16_t As[128 * 64];
  __shared__ uint16_t Bs[128 * 64];
  const int flat = blockIdx.x;                 // 512 blocks
  const int l = (flat & 7) * 64 + (flat >> 3);
  const int bx = l & 7, by = l >> 3;
  const int tid  = threadIdx.x;
  const int lane = tid & 63;
  const int wave = tid >> 6;
  const int wr = wave >> 1, wc = wave & 1;
  const int m0 = by * 128, n0 = bx * 128;
  const int lrow = lane & 15;
  const int grp  = lane >> 4;
  const int l8   = lane >> 3;
  const int c8   = lane & 7;

  f32x4 acc[4][4] = {};

  for (int k0 = 0; k0 < 1024; k0 += 64) {
#pragma unroll
    for (int it = 0; it < 4; ++it) {
      const int chunk = wave * 4 + it;
      const int row = chunk * 8 + l8;
      gl_lds16(&A [(size_t)(m0 + row) * 1024 + k0 + c8 * 8], &As[chunk * 512]);
      gl_lds16(&Bt[(size_t)(n0 + row) * 1024 + k0 + c8 * 8], &Bs[chunk * 512]);
    }
    __syncthreads();
#pragma unroll
    for (int ks = 0; ks < 2; ++ks) {
      bf16x8 af[4], bfr[4];
#pragma unroll
      for (int i = 0; i < 4; ++i) {
        af [i] = ldbf8(&As[(wr * 64 + i * 16 + lrow) * 64 + ks * 32 + grp * 8]);
        bfr[i] = ldbf8(&Bs[(wc * 64 + i * 16 + lrow) * 64 + ks * 32 + grp * 8]);
      }
#pragma unroll
      for (int i = 0; i < 4; ++i)
#pragma unroll
        for (int j = 0; j < 4; ++j)
          acc[i][j] = MFMA16(af[i], bfr[j], acc[i][j]);
    }
    __syncthreads();
  }

  const int r0 = grp * 4;
#pragma unroll
  for (int i = 0; i < 4; ++i) {
#pragma unroll
    for (int j = 0; j < 4; ++j) {
      int gmb = m0 + wr * 64 + i * 16 + r0;
      int gn  = n0 + wc * 64 + j * 16 + lrow;
      float bv = bias[gn];
#pragma unroll
      for (int r = 0; r < 4; ++r)
        out[(size_t)(gmb + r) * 1024 + gn] = acc[i][j][r] + bv;
    }
  }
}

// ---------------- Attention ----------------
// LDS tile: element (row, colblk c) at lds[row*64 + (c ^ (row&7))*8]
// (linear gload_lds writes; XOR applied on pre-swizzled source + read side)
__device__ __forceinline__ bf16x8 rd_tile(const uint16_t* t, int r, int s) {
  return ldbf8(&t[r * 64 + ((s ^ (r & 7)) * 8)]);
}

#define QBLK 128
// 1D grid 1024 (XCD-swizzled), 512 thr = 8 waves; wave owns 16 q rows.
// mfma(K,Q): lane holds scores for q=lane&15, k_loc=(lane>>4)*4+r.
__global__ __launch_bounds__(512)
void attn_kernel(const uint16_t* __restrict__ Q, const uint16_t* __restrict__ Kb,
                 const uint16_t* __restrict__ Vt, float* __restrict__ attnw,
                 uint16_t* __restrict__ ctx) {
  __shared__ uint16_t Ks[2][64 * 64];
  __shared__ uint16_t Vs[2][64 * 64];
  __shared__ uint16_t Pl[8][16 * 72];
  const int tid  = threadIdx.x;
  const int lane = tid & 63;
  const int wave = tid >> 6;          // 0..7
  const int flat = blockIdx.x;        // 1024 blocks
  const int lb = (flat & 7) * 128 + (flat >> 3);   // 128 consecutive per XCD
  const int qt = lb & 15, h = (lb >> 4) & 15, b = lb >> 8;
  const int q0 = qt * QBLK + wave * 16;
  const int lrow = lane & 15;
  const int grp  = lane >> 4;
  const float c = 0.125f * 1.44269504088896f;  // (1/sqrt(64)) * log2(e)

  const uint16_t* Kh = Kb + (size_t)(b * SEQ) * D_MODEL + h * HDIM;   // [s][d] str 1024
  const uint16_t* Vh = Vt + ((size_t)(b * NHEADS + h) * HDIM) * SEQ;  // [d][s] str 2048

  const size_t qbase = ((size_t)(b * SEQ) + q0 + lrow) * D_MODEL + h * HDIM;
  const bf16x8 qf0 = ldbf8(&Q[qbase + grp * 8]);
  const bf16x8 qf1 = ldbf8(&Q[qbase + 32 + grp * 8]);

  // staging coords: wave stages rows [wave*8, wave*8+8) of each 64x64 tile
  const int srow = wave * 8 + (lane >> 3);
  const int scb  = (lane & 7) ^ (srow & 7);        // pre-swizzled source col-blk

  // ---- pass A: online max+sum; K double-buffered (R4 structure) ----
  float m = -INFINITY, l = 0.f;
  gl_lds16(&Kh[(size_t)srow * D_MODEL + scb * 8], &Ks[0][wave * 512]);
#pragma unroll 1
  for (int kc = 0; kc < SEQ / 64; ++kc) {
    const int cur = kc & 1;
    __syncthreads();   // cur staged across waves; prev readers of cur^1 done
    if (kc + 1 < SEQ / 64)
      gl_lds16(&Kh[(size_t)((kc + 1) * 64 + srow) * D_MODEL + scb * 8],
               &Ks[cur ^ 1][wave * 512]);
    const uint16_t* kt_ = Ks[cur];
    f32x4 s[4];
#pragma unroll
    for (int kt = 0; kt < 4; ++kt) {
      f32x4 a = {};
      a = MFMA16(rd_tile(kt_, kt * 16 + lrow, grp),     qf0, a);
      a = MFMA16(rd_tile(kt_, kt * 16 + lrow, 4 + grp), qf1, a);
      s[kt] = a;
    }
    float v[16];
#pragma unroll
    for (int kt = 0; kt < 4; ++kt)
#pragma unroll
      for (int r = 0; r < 4; ++r) v[kt * 4 + r] = s[kt][r] * c;
    float mx = v[0];
#pragma unroll
    for (int i = 1; i < 16; ++i) mx = fmaxf(mx, v[i]);
    float mn = fmaxf(m, mx);
    float sum = 0.f;
#pragma unroll
    for (int i = 0; i < 16; ++i) sum += __builtin_amdgcn_exp2f(v[i] - mn);
    l = l * __builtin_amdgcn_exp2f(m - mn) + sum;
    m = mn;
  }
#pragma unroll
  for (int d = 16; d <= 32; d <<= 1) {
    float mp = __shfl_xor(m, d), lp = __shfl_xor(l, d);
    float mn = fmaxf(m, mp);
    l = l * __builtin_amdgcn_exp2f(m - mn) + lp * __builtin_amdgcn_exp2f(mp - mn);
    m = mn;
  }
  const float rinv = 1.0f / l;

  // ---- pass B: recompute scores, weights + PV; K+V double-buffered ----
  f32x4 cacc[4] = {};
  uint16_t* pw = &Pl[wave][0];
  float* awc = attnw + (((size_t)(b * NHEADS + h)) * SEQ + q0) * SEQ;
  gl_lds16(&Kh[(size_t)srow * D_MODEL + scb * 8], &Ks[0][wave * 512]);
  gl_lds16(&Vh[(size_t)srow * SEQ + scb * 8],     &Vs[0][wave * 512]);
#pragma unroll 1
  for (int kc = 0; kc < SEQ / 64; ++kc) {
    const int cur = kc & 1;
    __syncthreads();
    if (kc + 1 < SEQ / 64) {
      gl_lds16(&Kh[(size_t)((kc + 1) * 64 + srow) * D_MODEL + scb * 8],
               &Ks[cur ^ 1][wave * 512]);
      gl_lds16(&Vh[(size_t)srow * SEQ + (kc + 1) * 64 + scb * 8],
               &Vs[cur ^ 1][wave * 512]);
    }
    const uint16_t* kt_ = Ks[cur];
    f32x4 s[4];
#pragma unroll
    for (int kt = 0; kt < 4; ++kt) {
      f32x4 a = {};
      a = MFMA16(rd_tile(kt_, kt * 16 + lrow, grp),     qf0, a);
      a = MFMA16(rd_tile(kt_, kt * 16 + lrow, 4 + grp), qf1, a);
      s[kt] = a;
    }
#pragma unroll
    for (int kt = 0; kt < 4; ++kt) {
      ushort4 w;
      w.x = f2bf(__builtin_amdgcn_exp2f(s[kt][0] * c - m) * rinv);
      w.y = f2bf(__builtin_amdgcn_exp2f(s[kt][1] * c - m) * rinv);
      w.z = f2bf(__builtin_amdgcn_exp2f(s[kt][2] * c - m) * rinv);
      w.w = f2bf(__builtin_amdgcn_exp2f(s[kt][3] * c - m) * rinv);
      *(ushort4*)&pw[lrow * 72 + kt * 16 + grp * 4] = w;
    }
    asm volatile("s_waitcnt lgkmcnt(0)" ::: "memory");
    // coalesced fp32 weight stores: 4 instrs x (4 q-rows x 256B)
#pragma unroll
    for (int ii = 0; ii < 4; ++ii) {
      int q = ii * 4 + grp;
      ushort4 t4 = *(const ushort4*)&pw[q * 72 + lrow * 4];
      float4 o = make_float4(bf2f(t4.x), bf2f(t4.y), bf2f(t4.z), bf2f(t4.w));
      *(float4*)&awc[(size_t)q * SEQ + kc * 64 + lrow * 4] = o;
    }
    // PV over this 64-key chunk
    const uint16_t* vt_ = Vs[cur];
#pragma unroll
    for (int ks = 0; ks < 2; ++ks) {
      const bf16x8 pf = ldbf8(&pw[lrow * 72 + ks * 32 + grp * 8]);
#pragma unroll
      for (int n = 0; n < 4; ++n) {
        const bf16x8 vf = rd_tile(vt_, n * 16 + lrow, ks * 4 + grp);
        cacc[n] = MFMA16(pf, vf, cacc[n]);
      }
    }
  }
  // ctx: lane holds ctx[q = grp*4+r][d = n*16+lrow]
#pragma unroll
  for (int n = 0; n < 4; ++n)
#pragma unroll
    for (int r = 0; r < 4; ++r) {
      int gq = q0 + grp * 4 + r;
      ctx[((size_t)(b * SEQ) + gq) * D_MODEL + h * HDIM + n * 16 + lrow] = f2bf(cacc[n][r]);
    }
}

// ---------------- launch ----------------
extern "C" void kernel_launch(void* const* d_in, const int* in_sizes, int n_in,
                              void* d_out, int out_size, void* d_ws, size_t ws_size,
                              hipStream_t stream) {
  const float* x  = (const float*)d_in[0];
  const float* wq = (const float*)d_in[1];
  const float* bq = (const float*)d_in[2];
  const float* wk = (const float*)d_in[3];
  const float* bk = (const float*)d_in[4];
  const float* wv = (const float*)d_in[5];
  const float* bv = (const float*)d_in[6];
  const float* wo = (const float*)d_in[7];
  const float* bo = (const float*)d_in[8];

  char* ws = (char*)d_ws;
  uint16_t* xb   = (uint16_t*)ws;                   // 16 MB (reused as ctx)
  uint16_t* wqkv = (uint16_t*)(ws + (16u << 20));   // 6 MB: wq|wk|wv rows
  uint16_t* wob  = (uint16_t*)(ws + (22u << 20));   // 2 MB (contiguous after wqkv)
  uint16_t* Qb   = (uint16_t*)(ws + (24u << 20));
  uint16_t* Kc   = (uint16_t*)(ws + (40u << 20));
  uint16_t* Vtb  = (uint16_t*)(ws + (56u << 20));
  uint16_t* ctx  = xb;

  float* outp  = (float*)d_out;
  float* attnw = outp + (size_t)NTOK * D_MODEL;

  {
    int n4 = (NTOK * D_MODEL) / 4;
    cvt_kernel<<<(n4 + 255) / 256, 256, 0, stream>>>(x, xb, n4);
    cvt_w_kernel<<<(4 * 262144) / 256, 256, 0, stream>>>(wq, wk, wv, wo, wqkv);
  }

  gemm_qkv<<<1536, 256, 0, stream>>>(xb, wqkv, bq, bk, bv, Qb, Kc, Vtb);

  attn_kernel<<<1024, 512, 0, stream>>>(Qb, Kc, Vtb, attnw, ctx);

  gemm_out<<<512, 256, 0, stream>>>(ctx, wob, bo, outp);
}

// Round 10
// 388.090 us; speedup vs baseline: 1.2848x; 1.2061x over previous
//
#include <hip/hip_runtime.h>
#include <cstdint>
#include <cstddef>

// MultiHeadSelfAttention: B=4 H=16 S=2048 D=1024 d=64
// d_out = [output fp32 (4,2048,1024)] ++ [attn_weights fp32 (4,16,2048,2048)]
//
// R10: attn reverted to R6 EXACTLY (proven 468us structure; R8/R9's 128-chunk
//      aliased pass-A staging was corrupting data). One new lever:
//      non-temporal stores for attn weights + final output (write-once data,
//      keeps K/V panels resident in L2).

#define D_MODEL 1024
#define NHEADS  16
#define HDIM    64
#define BATCH   4
#define SEQ     2048
#define NTOK    (BATCH*SEQ)   // 8192

typedef __bf16 bf16x8 __attribute__((ext_vector_type(8)));
typedef float  f32x4  __attribute__((ext_vector_type(4)));
typedef unsigned short u16x8 __attribute__((ext_vector_type(8)));

__device__ __forceinline__ uint16_t f2bf(float f) {
  union { float f; uint32_t u; } v; v.f = f;
  return (uint16_t)((v.u + 0x7FFFu + ((v.u >> 16) & 1u)) >> 16);
}
__device__ __forceinline__ float bf2f(uint16_t u) {
  union { uint32_t u; float f; } v; v.u = (uint32_t)u << 16; return v.f;
}
__device__ __forceinline__ bf16x8 ldbf8(const uint16_t* p) {
  return __builtin_bit_cast(bf16x8, *(const u16x8*)p);
}
__device__ __forceinline__ void nt_store4(float* p, float a, float b, float c, float d) {
  f32x4 v = { a, b, c, d };
  __builtin_nontemporal_store(v, (f32x4*)p);
}
#define MFMA16(a, b, c) __builtin_amdgcn_mfma_f32_16x16x32_bf16((a), (b), (c), 0, 0, 0)

// async global->LDS, 16B/lane; LDS dest = wave-uniform base + lane*16.
__device__ __forceinline__ void gl_lds16(const uint16_t* g, uint16_t* l) {
  __builtin_amdgcn_global_load_lds(
      (const __attribute__((address_space(1))) uint32_t*)g,
      (__attribute__((address_space(3))) uint32_t*)l, 16, 0, 0);
}

// ---------------- fp32 -> bf16 converts ----------------
__global__ __launch_bounds__(256) void cvt_kernel(const float* __restrict__ src,
                                                  uint16_t* __restrict__ dst, int n4) {
  int i = blockIdx.x * blockDim.x + threadIdx.x;
  if (i < n4) {
    float4 f = ((const float4*)src)[i];
    ushort4 o;
    o.x = f2bf(f.x); o.y = f2bf(f.y); o.z = f2bf(f.z); o.w = f2bf(f.w);
    ((ushort4*)dst)[i] = o;
  }
}
// all 4 weight matrices -> contiguous bf16 dst (wq|wk|wv|wo), one launch
__global__ __launch_bounds__(256)
void cvt_w_kernel(const float* __restrict__ wq, const float* __restrict__ wk,
                  const float* __restrict__ wv, const float* __restrict__ wo,
                  uint16_t* __restrict__ dst) {
  int i = blockIdx.x * blockDim.x + threadIdx.x;   // [0, 4*262144)
  int sel = i >> 18, off = i & 262143;
  const float* src = (sel == 0) ? wq : (sel == 1) ? wk : (sel == 2) ? wv : wo;
  float4 f = ((const float4*)src)[off];
  ushort4 o;
  o.x = f2bf(f.x); o.y = f2bf(f.y); o.z = f2bf(f.z); o.w = f2bf(f.w);
  ((ushort4*)dst)[i] = o;
}

// ---------------- fused QKV GEMM ----------------
// A[8192,1024] bf16; Wqkv[3072,1024] bf16 (rows: wq | wk | wv).
// seg 0 -> Qb bf16 [tok,1024]; seg 1 -> Kc bf16; seg 2 -> Vt bf16 [(b,h,d),s].
__global__ __launch_bounds__(256)
void gemm_qkv(const uint16_t* __restrict__ A, const uint16_t* __restrict__ Wqkv,
              const float* __restrict__ bq, const float* __restrict__ bk,
              const float* __restrict__ bv,
              uint16_t* __restrict__ Qb, uint16_t* __restrict__ Kc,
              uint16_t* __restrict__ Vt) {
  __shared__ uint16_t As[128 * 64];
  __shared__ uint16_t Bs[128 * 64];
  const int flat = blockIdx.x;                 // 1536 blocks
  const int l = (flat & 7) * 192 + (flat >> 3);
  const int bx = l % 24, by = l / 24;
  const int tid  = threadIdx.x;
  const int lane = tid & 63;
  const int wave = tid >> 6;
  const int wr = wave >> 1, wc = wave & 1;
  const int m0 = by * 128, n0 = bx * 128;
  const int lrow = lane & 15;
  const int grp  = lane >> 4;
  const int l8   = lane >> 3;
  const int c8   = lane & 7;

  f32x4 acc[4][4] = {};

  for (int k0 = 0; k0 < 1024; k0 += 64) {
#pragma unroll
    for (int it = 0; it < 4; ++it) {
      const int chunk = wave * 4 + it;
      const int row = chunk * 8 + l8;
      gl_lds16(&A   [(size_t)(m0 + row) * 1024 + k0 + c8 * 8], &As[chunk * 512]);
      gl_lds16(&Wqkv[(size_t)(n0 + row) * 1024 + k0 + c8 * 8], &Bs[chunk * 512]);
    }
    __syncthreads();
#pragma unroll
    for (int ks = 0; ks < 2; ++ks) {
      bf16x8 af[4], bfr[4];
#pragma unroll
      for (int i = 0; i < 4; ++i) {
        af [i] = ldbf8(&As[(wr * 64 + i * 16 + lrow) * 64 + ks * 32 + grp * 8]);
        bfr[i] = ldbf8(&Bs[(wc * 64 + i * 16 + lrow) * 64 + ks * 32 + grp * 8]);
      }
#pragma unroll
      for (int i = 0; i < 4; ++i)
#pragma unroll
        for (int j = 0; j < 4; ++j)
          acc[i][j] = MFMA16(af[i], bfr[j], acc[i][j]);
    }
    __syncthreads();
  }

  const int seg = n0 >> 10;                    // uniform per block
  const float* bp = (seg == 0) ? bq : (seg == 1) ? bk : bv;
  uint16_t* dst01 = (seg == 0) ? Qb : Kc;
  const int r0 = grp * 4;
#pragma unroll
  for (int i = 0; i < 4; ++i) {
#pragma unroll
    for (int j = 0; j < 4; ++j) {
      int gmb = m0 + wr * 64 + i * 16 + r0;
      int gn  = n0 + wc * 64 + j * 16 + lrow;
      int nloc = gn & 1023;
      float bv_ = bp[nloc];
#pragma unroll
      for (int r = 0; r < 4; ++r) {
        float v = acc[i][j][r] + bv_;
        int gm = gmb + r;
        if (seg < 2) {
          dst01[(size_t)gm * 1024 + nloc] = f2bf(v);
        } else {
          int b = gm >> 11, s = gm & (SEQ - 1);
          int h = nloc >> 6, d = nloc & (HDIM - 1);
          Vt[(((size_t)(b * NHEADS + h) * HDIM + d) << 11) + s] = f2bf(v);
        }
      }
    }
  }
}

// ---------------- out-proj GEMM (fp32 out, non-temporal) ----------------
__global__ __launch_bounds__(256)
void gemm_out(const uint16_t* __restrict__ A, const uint16_t* __restrict__ Bt,
              const float* __restrict__ bias, float* __restrict__ out) {
  __shared__ uint16_t As[128 * 64];
  __shared__ uint16_t Bs[128 * 64];
  const int flat = blockIdx.x;                 // 512 blocks
  const int l = (flat & 7) * 64 + (flat >> 3);
  const int bx = l & 7, by = l >> 3;
  const int tid  = threadIdx.x;
  const int lane = tid & 63;
  const int wave = tid >> 6;
  const int wr = wave >> 1, wc = wave & 1;
  const int m0 = by * 128, n0 = bx * 128;
  const int lrow = lane & 15;
  const int grp  = lane >> 4;
  const int l8   = lane >> 3;
  const int c8   = lane & 7;

  f32x4 acc[4][4] = {};

  for (int k0 = 0; k0 < 1024; k0 += 64) {
#pragma unroll
    for (int it = 0; it < 4; ++it) {
      const int chunk = wave * 4 + it;
      const int row = chunk * 8 + l8;
      gl_lds16(&A [(size_t)(m0 + row) * 1024 + k0 + c8 * 8], &As[chunk * 512]);
      gl_lds16(&Bt[(size_t)(n0 + row) * 1024 + k0 + c8 * 8], &Bs[chunk * 512]);
    }
    __syncthreads();
#pragma unroll
    for (int ks = 0; ks < 2; ++ks) {
      bf16x8 af[4], bfr[4];
#pragma unroll
      for (int i = 0; i < 4; ++i) {
        af [i] = ldbf8(&As[(wr * 64 + i * 16 + lrow) * 64 + ks * 32 + grp * 8]);
        bfr[i] = ldbf8(&Bs[(wc * 64 + i * 16 + lrow) * 64 + ks * 32 + grp * 8]);
      }
#pragma unroll
      for (int i = 0; i < 4; ++i)
#pragma unroll
        for (int j = 0; j < 4; ++j)
          acc[i][j] = MFMA16(af[i], bfr[j], acc[i][j]);
    }
    __syncthreads();
  }

  const int r0 = grp * 4;
#pragma unroll
  for (int i = 0; i < 4; ++i) {
#pragma unroll
    for (int j = 0; j < 4; ++j) {
      int gmb = m0 + wr * 64 + i * 16 + r0;
      int gn  = n0 + wc * 64 + j * 16 + lrow;
      float bv = bias[gn];
#pragma unroll
      for (int r = 0; r < 4; ++r)
        __builtin_nontemporal_store(acc[i][j][r] + bv,
                                    &out[(size_t)(gmb + r) * 1024 + gn]);
    }
  }
}

// ---------------- Attention (R6 structure, verbatim + nt weight stores) ----
// LDS tile: element (row, colblk c) at lds[row*64 + (c ^ (row&7))*8]
// (linear gload_lds writes; XOR applied on pre-swizzled source + read side)
__device__ __forceinline__ bf16x8 rd_tile(const uint16_t* t, int r, int s) {
  return ldbf8(&t[r * 64 + ((s ^ (r & 7)) * 8)]);
}

#define QBLK 128
// 1D grid 1024 (XCD-swizzled), 512 thr = 8 waves; wave owns 16 q rows.
// mfma(K,Q): lane holds scores for q=lane&15, k_loc=(lane>>4)*4+r.
__global__ __launch_bounds__(512)
void attn_kernel(const uint16_t* __restrict__ Q, const uint16_t* __restrict__ Kb,
                 const uint16_t* __restrict__ Vt, float* __restrict__ attnw,
                 uint16_t* __restrict__ ctx) {
  __shared__ uint16_t Ks[2][64 * 64];
  __shared__ uint16_t Vs[2][64 * 64];
  __shared__ uint16_t Pl[8][16 * 72];
  const int tid  = threadIdx.x;
  const int lane = tid & 63;
  const int wave = tid >> 6;          // 0..7
  const int flat = blockIdx.x;        // 1024 blocks
  const int lb = (flat & 7) * 128 + (flat >> 3);   // 128 consecutive per XCD
  const int qt = lb & 15, h = (lb >> 4) & 15, b = lb >> 8;
  const int q0 = qt * QBLK + wave * 16;
  const int lrow = lane & 15;
  const int grp  = lane >> 4;
  const float c = 0.125f * 1.44269504088896f;  // (1/sqrt(64)) * log2(e)

  const uint16_t* Kh = Kb + (size_t)(b * SEQ) * D_MODEL + h * HDIM;   // [s][d] str 1024
  const uint16_t* Vh = Vt + ((size_t)(b * NHEADS + h) * HDIM) * SEQ;  // [d][s] str 2048

  const size_t qbase = ((size_t)(b * SEQ) + q0 + lrow) * D_MODEL + h * HDIM;
  const bf16x8 qf0 = ldbf8(&Q[qbase + grp * 8]);
  const bf16x8 qf1 = ldbf8(&Q[qbase + 32 + grp * 8]);

  // staging coords: wave stages rows [wave*8, wave*8+8) of each 64x64 tile
  const int srow = wave * 8 + (lane >> 3);
  const int scb  = (lane & 7) ^ (srow & 7);        // pre-swizzled source col-blk

  // ---- pass A: online max+sum; K double-buffered ----
  float m = -INFINITY, l = 0.f;
  gl_lds16(&Kh[(size_t)srow * D_MODEL + scb * 8], &Ks[0][wave * 512]);
#pragma unroll 1
  for (int kc = 0; kc < SEQ / 64; ++kc) {
    const int cur = kc & 1;
    __syncthreads();   // cur staged across waves; prev readers of cur^1 done
    if (kc + 1 < SEQ / 64)
      gl_lds16(&Kh[(size_t)((kc + 1) * 64 + srow) * D_MODEL + scb * 8],
               &Ks[cur ^ 1][wave * 512]);
    const uint16_t* kt_ = Ks[cur];
    f32x4 s[4];
#pragma unroll
    for (int kt = 0; kt < 4; ++kt) {
      f32x4 a = {};
      a = MFMA16(rd_tile(kt_, kt * 16 + lrow, grp),     qf0, a);
      a = MFMA16(rd_tile(kt_, kt * 16 + lrow, 4 + grp), qf1, a);
      s[kt] = a;
    }
    float v[16];
#pragma unroll
    for (int kt = 0; kt < 4; ++kt)
#pragma unroll
      for (int r = 0; r < 4; ++r) v[kt * 4 + r] = s[kt][r] * c;
    float mx = v[0];
#pragma unroll
    for (int i = 1; i < 16; ++i) mx = fmaxf(mx, v[i]);
    float mn = fmaxf(m, mx);
    float sum = 0.f;
#pragma unroll
    for (int i = 0; i < 16; ++i) sum += __builtin_amdgcn_exp2f(v[i] - mn);
    l = l * __builtin_amdgcn_exp2f(m - mn) + sum;
    m = mn;
  }
#pragma unroll
  for (int d = 16; d <= 32; d <<= 1) {
    float mp = __shfl_xor(m, d), lp = __shfl_xor(l, d);
    float mn = fmaxf(m, mp);
    l = l * __builtin_amdgcn_exp2f(m - mn) + lp * __builtin_amdgcn_exp2f(mp - mn);
    m = mn;
  }
  const float rinv = 1.0f / l;

  // ---- pass B: recompute scores, weights + PV; K+V double-buffered ----
  f32x4 cacc[4] = {};
  uint16_t* pw = &Pl[wave][0];
  float* awc = attnw + (((size_t)(b * NHEADS + h)) * SEQ + q0) * SEQ;
  gl_lds16(&Kh[(size_t)srow * D_MODEL + scb * 8], &Ks[0][wave * 512]);
  gl_lds16(&Vh[(size_t)srow * SEQ + scb * 8],     &Vs[0][wave * 512]);
#pragma unroll 1
  for (int kc = 0; kc < SEQ / 64; ++kc) {
    const int cur = kc & 1;
    __syncthreads();
    if (kc + 1 < SEQ / 64) {
      gl_lds16(&Kh[(size_t)((kc + 1) * 64 + srow) * D_MODEL + scb * 8],
               &Ks[cur ^ 1][wave * 512]);
      gl_lds16(&Vh[(size_t)srow * SEQ + (kc + 1) * 64 + scb * 8],
               &Vs[cur ^ 1][wave * 512]);
    }
    const uint16_t* kt_ = Ks[cur];
    f32x4 s[4];
#pragma unroll
    for (int kt = 0; kt < 4; ++kt) {
      f32x4 a = {};
      a = MFMA16(rd_tile(kt_, kt * 16 + lrow, grp),     qf0, a);
      a = MFMA16(rd_tile(kt_, kt * 16 + lrow, 4 + grp), qf1, a);
      s[kt] = a;
    }
#pragma unroll
    for (int kt = 0; kt < 4; ++kt) {
      ushort4 w;
      w.x = f2bf(__builtin_amdgcn_exp2f(s[kt][0] * c - m) * rinv);
      w.y = f2bf(__builtin_amdgcn_exp2f(s[kt][1] * c - m) * rinv);
      w.z = f2bf(__builtin_amdgcn_exp2f(s[kt][2] * c - m) * rinv);
      w.w = f2bf(__builtin_amdgcn_exp2f(s[kt][3] * c - m) * rinv);
      *(ushort4*)&pw[lrow * 72 + kt * 16 + grp * 4] = w;
    }
    asm volatile("s_waitcnt lgkmcnt(0)" ::: "memory");
    // coalesced fp32 weight stores (non-temporal): 4 x (4 q-rows x 256B)
#pragma unroll
    for (int ii = 0; ii < 4; ++ii) {
      int q = ii * 4 + grp;
      ushort4 t4 = *(const ushort4*)&pw[q * 72 + lrow * 4];
      nt_store4(&awc[(size_t)q * SEQ + kc * 64 + lrow * 4],
                bf2f(t4.x), bf2f(t4.y), bf2f(t4.z), bf2f(t4.w));
    }
    // PV over this 64-key chunk
    const uint16_t* vt_ = Vs[cur];
#pragma unroll
    for (int ks = 0; ks < 2; ++ks) {
      const bf16x8 pf = ldbf8(&pw[lrow * 72 + ks * 32 + grp * 8]);
#pragma unroll
      for (int n = 0; n < 4; ++n) {
        const bf16x8 vf = rd_tile(vt_, n * 16 + lrow, ks * 4 + grp);
        cacc[n] = MFMA16(pf, vf, cacc[n]);
      }
    }
  }
  // ctx: lane holds ctx[q = grp*4+r][d = n*16+lrow]
#pragma unroll
  for (int n = 0; n < 4; ++n)
#pragma unroll
    for (int r = 0; r < 4; ++r) {
      int gq = q0 + grp * 4 + r;
      ctx[((size_t)(b * SEQ) + gq) * D_MODEL + h * HDIM + n * 16 + lrow] = f2bf(cacc[n][r]);
    }
}

// ---------------- launch ----------------
extern "C" void kernel_launch(void* const* d_in, const int* in_sizes, int n_in,
                              void* d_out, int out_size, void* d_ws, size_t ws_size,
                              hipStream_t stream) {
  const float* x  = (const float*)d_in[0];
  const float* wq = (const float*)d_in[1];
  const float* bq = (const float*)d_in[2];
  const float* wk = (const float*)d_in[3];
  const float* bk = (const float*)d_in[4];
  const float* wv = (const float*)d_in[5];
  const float* bv = (const float*)d_in[6];
  const float* wo = (const float*)d_in[7];
  const float* bo = (const float*)d_in[8];

  char* ws = (char*)d_ws;
  uint16_t* xb   = (uint16_t*)ws;                   // 16 MB (reused as ctx)
  uint16_t* wqkv = (uint16_t*)(ws + (16u << 20));   // 6 MB: wq|wk|wv rows
  uint16_t* wob  = (uint16_t*)(ws + (22u << 20));   // 2 MB (contiguous after wqkv)
  uint16_t* Qb   = (uint16_t*)(ws + (24u << 20));
  uint16_t* Kc   = (uint16_t*)(ws + (40u << 20));
  uint16_t* Vtb  = (uint16_t*)(ws + (56u << 20));
  uint16_t* ctx  = xb;

  float* outp  = (float*)d_out;
  float* attnw = outp + (size_t)NTOK * D_MODEL;

  {
    int n4 = (NTOK * D_MODEL) / 4;
    cvt_kernel<<<(n4 + 255) / 256, 256, 0, stream>>>(x, xb, n4);
    cvt_w_kernel<<<(4 * 262144) / 256, 256, 0, stream>>>(wq, wk, wv, wo, wqkv);
  }

  gemm_qkv<<<1536, 256, 0, stream>>>(xb, wqkv, bq, bk, bv, Qb, Kc, Vtb);

  attn_kernel<<<1024, 512, 0, stream>>>(Qb, Kc, Vtb, attnw, ctx);

  gemm_out<<<512, 256, 0, stream>>>(ctx, wob, bo, outp);
}